// Round 6
// baseline (446.279 us; speedup 1.0000x reference)
//
#include <hip/hip_runtime.h>
#include <stdint.h>

typedef unsigned short u16;
typedef __attribute__((ext_vector_type(8))) short bf16x8;
typedef __attribute__((ext_vector_type(4))) float f32x4;

#define MFMA16(a, b, c) __builtin_amdgcn_mfma_f32_16x16x32_bf16((a), (b), (c), 0, 0, 0)

__device__ __forceinline__ float b2f(u16 u) {
    union { unsigned int i; float f; } v; v.i = ((unsigned int)u) << 16; return v.f;
}
__device__ __forceinline__ u16 f2b(float f) {
    union { float f; unsigned int i; } v; v.f = f;
    unsigned int r = v.i + 0x7fffu + ((v.i >> 16) & 1u);
    return (u16)(r >> 16);
}

typedef __attribute__((address_space(1))) void gvoid;
typedef __attribute__((address_space(3))) void lvoid;
__device__ __forceinline__ void gld16(const void* g, void* l) {
    __builtin_amdgcn_global_load_lds((gvoid*)(void*)g, (lvoid*)l, 16, 0, 0);
}

// Panel-swizzled block mapping: 8-row-tile panels, col-major inside a panel.
__device__ __forceinline__ void tile_from_bid(int bid, int nTM, int nTN,
                                              int& rt, int& ct) {
    const int PW = 8;
    const int full = nTM / PW;
    const int per = PW * nTN;
    int p = bid / per;
    int pw = PW;
    int rem = bid - p * per;
    if (p >= full) { p = full; rem = bid - full * per; pw = nTM - full * PW; }
    const int c = rem / pw;
    const int r = rem - c * pw;
    rt = p * PW + r;
    ct = c;
}

// ---------------------------------------------------------------------------
// fp32 -> bf16 elementwise convert (n multiple of 4)
// ---------------------------------------------------------------------------
__global__ __launch_bounds__(256) void f32_to_bf16(const float* __restrict__ in,
                                                   u16* __restrict__ out, int n) {
    const int i = (blockIdx.x * 256 + threadIdx.x) * 4;
    if (i + 3 < n) {
        const float4 v = *(const float4*)(in + i);
        ushort4 o;
        o.x = f2b(v.x); o.y = f2b(v.y); o.z = f2b(v.z); o.w = f2b(v.w);
        *(ushort4*)(out + i) = o;
    }
}

// ---------------------------------------------------------------------------
// fused transpose + fp32->bf16: out[C x R](bf16) = in[R x C](f32)^T
// ---------------------------------------------------------------------------
__global__ __launch_bounds__(256) void transpose_f32_bf16(const float* __restrict__ in,
                                                          u16* __restrict__ out,
                                                          int R, int C) {
    __shared__ float tile[32][33];
    const int t = threadIdx.x;
    const int r = t >> 3, c4 = (t & 7) * 4;
    const int ir = blockIdx.y * 32 + r, ic = blockIdx.x * 32 + c4;
    const float4 v = *(const float4*)(in + (size_t)ir * C + ic);
    tile[r][c4 + 0] = v.x; tile[r][c4 + 1] = v.y;
    tile[r][c4 + 2] = v.z; tile[r][c4 + 3] = v.w;
    __syncthreads();
    const int orow = blockIdx.x * 32 + r, ocol = blockIdx.y * 32 + c4;
    ushort4 o;
    o.x = f2b(tile[c4 + 0][r]); o.y = f2b(tile[c4 + 1][r]);
    o.z = f2b(tile[c4 + 2][r]); o.w = f2b(tile[c4 + 3][r]);
    *(ushort4*)(out + (size_t)orow * R + ocol) = o;
}

// ---------------------------------------------------------------------------
// C = A(bf16)[M x K] * Bt(bf16)[N x K]^T + bias(f32)[N]
// 128x128 tile, BK=64, 256 threads (4 waves 2x2 over 64x64), global_load_lds.
// EPI: 0 = bf16 store; 1 = f32 atomicAdd (split-K via blockIdx.z, bias on z=0);
//      2 = fused qkv epilogue:
//          Q/K col-tiles: RoPE (pair via shfl_xor) -> qkv bf16 (stride 1536);
//          V col-tiles: MFMA operands SWAPPED in K-loop so D rows=d, cols=n
//            -> coalesced 32B stores into VtG[bh][d(64)][n(640)].
// ---------------------------------------------------------------------------
template <int EPI>
__global__ __launch_bounds__(256) void gemm_bt(const u16* __restrict__ A,
                                               const u16* __restrict__ Bt,
                                               const float* __restrict__ bias,
                                               void* __restrict__ Cv,
                                               const float* __restrict__ cosp,
                                               const float* __restrict__ sinp,
                                               u16* __restrict__ VtG,
                                               int M, int N, int K) {
    __shared__ __align__(16) u16 As[128 * 64];
    __shared__ __align__(16) u16 Bs[128 * 64];

    const int t = threadIdx.x;
    const int lane = t & 63;
    const int wave = t >> 6;
    const int l15 = lane & 15, quad = lane >> 4;
    const int wm = wave >> 1, wn = wave & 1;

    int rt, ct;
    tile_from_bid(blockIdx.y * gridDim.x + blockIdx.x, gridDim.x, gridDim.y, rt, ct);
    const int row0 = rt * 128;
    const int col0 = ct * 128;
    const bool vblk = (EPI == 2) && (col0 >= 1536);

    // split-K support (EPI==1): z selects K half
    const int koff = (EPI == 1) ? (int)blockIdx.z * (K >> 1) : 0;
    const int nKT = (EPI == 1) ? (K >> 7) : (K >> 6);

    const f32x4 fz = {0.f, 0.f, 0.f, 0.f};
    f32x4 acc[4][4];
#pragma unroll
    for (int i = 0; i < 4; ++i)
#pragma unroll
        for (int j = 0; j < 4; ++j) acc[i][j] = fz;

    const u16* Ap[4]; u16* Al[4];
    const u16* Bp[4]; u16* Bl[4];
#pragma unroll
    for (int n = 0; n < 4; ++n) {
        const int c = t + n * 256;
        const int row = ((c >> 7) << 4) + (c & 15);
        const int kc = (c >> 4) & 7;
        int ar = row0 + row; if (ar > M - 1) ar = M - 1;   // clamp partial M tile
        Ap[n] = A + (size_t)ar * K + koff + kc * 8;
        Al[n] = As + (size_t)c * 8;
        Bp[n] = Bt + (size_t)(col0 + row) * K + koff + kc * 8;  // N % 128 == 0
        Bl[n] = Bs + (size_t)c * 8;
    }

    for (int kt = 0; kt < nKT; ++kt) {
        __syncthreads();
        const int kb = kt << 6;
#pragma unroll
        for (int n = 0; n < 4; ++n) gld16(Ap[n] + kb, Al[n]);
#pragma unroll
        for (int n = 0; n < 4; ++n) gld16(Bp[n] + kb, Bl[n]);
        __syncthreads();
#pragma unroll
        for (int kk = 0; kk < 2; ++kk) {
            bf16x8 af[4], bfr[4];
#pragma unroll
            for (int mi = 0; mi < 4; ++mi)
                af[mi] = *(const bf16x8*)(As + ((size_t)((wm * 4 + mi) * 128 + (kk * 4 + quad) * 16 + l15)) * 8);
#pragma unroll
            for (int ni = 0; ni < 4; ++ni)
                bfr[ni] = *(const bf16x8*)(Bs + ((size_t)((wn * 4 + ni) * 128 + (kk * 4 + quad) * 16 + l15)) * 8);
            if (vblk) {
#pragma unroll
                for (int mi = 0; mi < 4; ++mi)
#pragma unroll
                    for (int ni = 0; ni < 4; ++ni)
                        acc[mi][ni] = MFMA16(bfr[ni], af[mi], acc[mi][ni]);
            } else {
#pragma unroll
                for (int mi = 0; mi < 4; ++mi)
#pragma unroll
                    for (int ni = 0; ni < 4; ++ni)
                        acc[mi][ni] = MFMA16(af[mi], bfr[ni], acc[mi][ni]);
            }
        }
    }

    if (EPI == 2 && vblk) {
        // ---- V tiles, operand-swapped: D rows (quad*4+r) = col/d,
        //      D cols (l15) = token row -> coalesced VtG stores along n ----
#pragma unroll
        for (int ni = 0; ni < 4; ++ni) {
#pragma unroll
            for (int r = 0; r < 4; ++r) {
                const int col = col0 + wn * 64 + ni * 16 + quad * 4 + r;
                const float bv = bias[col];
                const int hd = (col - 1536) >> 6;
                const int d = col & 63;
#pragma unroll
                for (int mi = 0; mi < 4; ++mi) {
                    const int row = row0 + wm * 64 + mi * 16 + l15;
                    if (row < M) {
                        const int bb = row / 577, n = row - bb * 577;
                        VtG[((size_t)(bb * 12 + hd) * 64 + d) * 640 + n] =
                            f2b(acc[mi][ni][r] + bv);
                    }
                }
            }
        }
    } else if (EPI == 2) {
        // ---- Q/K tiles: bias + RoPE -> 1536-stride qkv ----
        float bvv[4];
#pragma unroll
        for (int ni = 0; ni < 4; ++ni) bvv[ni] = bias[col0 + wn * 64 + ni * 16 + l15];
#pragma unroll
        for (int mi = 0; mi < 4; ++mi) {
#pragma unroll
            for (int r = 0; r < 4; ++r) {
                const int row = row0 + wm * 64 + mi * 16 + quad * 4 + r;
                if (row < M) {
                    const int bb = row / 577, n = row - bb * 577;
                    const float* cb = cosp + (size_t)(n - 1) * 32;
                    const float* sb = sinp + (size_t)(n - 1) * 32;
                    u16* outp = (u16*)Cv + (size_t)row * 1536;
#pragma unroll
                    for (int ni = 0; ni < 4; ++ni) {
                        const int col = col0 + wn * 64 + ni * 16 + l15;
                        const float v = acc[mi][ni][r] + bvv[ni];
                        const float p = __shfl_xor(v, 1);
                        const int d = col & 63;
                        float c = 1.f, s = 0.f;
                        if (n >= 1) { c = cb[d >> 1]; s = sb[d >> 1]; }
                        const float rv = ((d & 1) == 0) ? (v * c - p * s)
                                                        : (p * s + v * c);
                        outp[col] = f2b(rv);
                    }
                }
            }
        }
    } else {
#pragma unroll
        for (int ni = 0; ni < 4; ++ni) {
            const int col = col0 + wn * 64 + ni * 16 + l15;
            const float bv = (EPI == 1 && blockIdx.z != 0) ? 0.f : bias[col];
#pragma unroll
            for (int mi = 0; mi < 4; ++mi) {
#pragma unroll
                for (int r = 0; r < 4; ++r) {
                    const int row = row0 + wm * 64 + mi * 16 + quad * 4 + r;
                    if (row < M) {
                        const float val = acc[mi][ni][r] + bv;
                        if (EPI == 1)
                            atomicAdd(&((float*)Cv)[(size_t)row * N + col], val);
                        else
                            ((u16*)Cv)[(size_t)row * N + col] = f2b(val);
                    }
                }
            }
        }
    }
}

// ---------------------------------------------------------------------------
// Flash attention (unchanged from round 5): block = (64-query tile, bh).
// qkv 1536-stride (Q 0..767, K 768..1535), RoPE pre-applied; V in VtG.
// ---------------------------------------------------------------------------
#define PSTR 80

__global__ __launch_bounds__(256) void attn2(const u16* __restrict__ qkv,
                                             const u16* __restrict__ VtG,
                                             u16* __restrict__ aout) {
    __shared__ __align__(16) u16 Ks[64 * 64];
    __shared__ __align__(16) u16 Vs[64 * 64];
    __shared__ __align__(16) u16 Pb[4 * 16 * PSTR];

    const int t = threadIdx.x;
    const int lane = t & 63, wave = t >> 6;
    const int l15 = lane & 15, quad = lane >> 4;
    const int qt = blockIdx.x;          // 0..9
    const int bh = blockIdx.y;          // 0..191
    const int b = bh / 12, h = bh - b * 12;
    const u16* baseQ = qkv + (size_t)b * 577 * 1536 + h * 64;
    const u16* baseK = baseQ + 768;
    const u16* vbase = VtG + (size_t)bh * 64 * 640;

    const int mq = qt * 64 + wave * 16 + l15;
    const int nq = mq < 577 ? mq : 576;
    bf16x8 aq[2];
    aq[0] = *(const bf16x8*)(baseQ + (size_t)nq * 1536 + quad * 8);
    aq[1] = *(const bf16x8*)(baseQ + (size_t)nq * 1536 + 32 + quad * 8);

    const int r15 = t & 15, cc = (t >> 4) & 7, rg0 = t >> 7;
    const int row0 = rg0 * 16 + r15, row1 = row0 + 32;
    u16* kl0 = Ks + t * 8;  u16* kl1 = Ks + (t + 256) * 8;
    u16* vl0 = Vs + t * 8;  u16* vl1 = Vs + (t + 256) * 8;
    const u16* vp0 = vbase + (size_t)row0 * 640 + cc * 8;
    const u16* vp1 = vbase + (size_t)row1 * 640 + cc * 8;

    u16* Pw = Pb + wave * 16 * PSTR;

    f32x4 oacc[4];
    const f32x4 fz = {0.f, 0.f, 0.f, 0.f};
#pragma unroll
    for (int i = 0; i < 4; ++i) oacc[i] = fz;
    float m4[4] = {-1e30f, -1e30f, -1e30f, -1e30f};
    float l4[4] = {0.f, 0.f, 0.f, 0.f};

    for (int kt = 0; kt < 10; ++kt) {
        __syncthreads();
        {
            int n0 = kt * 64 + row0; if (n0 > 576) n0 = 576;
            int n1 = kt * 64 + row1; if (n1 > 576) n1 = 576;
            gld16(baseK + (size_t)n0 * 1536 + cc * 8, kl0);
            gld16(baseK + (size_t)n1 * 1536 + cc * 8, kl1);
            gld16(vp0 + kt * 64, vl0);
            gld16(vp1 + kt * 64, vl1);
        }
        __syncthreads();

        f32x4 sacc[4];
#pragma unroll
        for (int nt = 0; nt < 4; ++nt) {
            sacc[nt] = fz;
#pragma unroll
            for (int kk = 0; kk < 2; ++kk) {
                const bf16x8 bk = *(const bf16x8*)(Ks + (nt * 128 + (kk * 4 + quad) * 16 + l15) * 8);
                sacc[nt] = MFMA16(aq[kk], bk, sacc[nt]);
            }
        }
        float sv[4][4];
#pragma unroll
        for (int nt = 0; nt < 4; ++nt) {
            const int key = kt * 64 + nt * 16 + l15;
            const bool kvalid = key < 577;
#pragma unroll
            for (int r = 0; r < 4; ++r)
                sv[nt][r] = kvalid ? sacc[nt][r] * 0.125f : -1e30f;
        }
        float mt[4];
#pragma unroll
        for (int r = 0; r < 4; ++r) {
            mt[r] = fmaxf(fmaxf(sv[0][r], sv[1][r]), fmaxf(sv[2][r], sv[3][r]));
#pragma unroll
            for (int off = 1; off <= 8; off <<= 1)
                mt[r] = fmaxf(mt[r], __shfl_xor(mt[r], off));
        }
        float alpha[4];
#pragma unroll
        for (int r = 0; r < 4; ++r) {
            const float mnew = fmaxf(m4[r], mt[r]);
            alpha[r] = __expf(m4[r] - mnew);
            m4[r] = mnew;
        }
        float lsum[4] = {0.f, 0.f, 0.f, 0.f};
#pragma unroll
        for (int nt = 0; nt < 4; ++nt) {
#pragma unroll
            for (int r = 0; r < 4; ++r) {
                const float p = __expf(sv[nt][r] - m4[r]);
                lsum[r] += p;
                Pw[(quad * 4 + r) * PSTR + nt * 16 + l15] = f2b(p);
            }
        }
#pragma unroll
        for (int r = 0; r < 4; ++r) {
#pragma unroll
            for (int off = 1; off <= 8; off <<= 1)
                lsum[r] += __shfl_xor(lsum[r], off);
            l4[r] = l4[r] * alpha[r] + lsum[r];
        }
#pragma unroll
        for (int dt = 0; dt < 4; ++dt)
#pragma unroll
            for (int r = 0; r < 4; ++r) oacc[dt][r] *= alpha[r];

        __asm__ __volatile__("s_waitcnt lgkmcnt(0)" ::: "memory");

#pragma unroll
        for (int kc = 0; kc < 2; ++kc) {
            const bf16x8 pf = *(const bf16x8*)(Pw + l15 * PSTR + kc * 32 + quad * 8);
#pragma unroll
            for (int dt = 0; dt < 4; ++dt) {
                const bf16x8 vf = *(const bf16x8*)(Vs + (dt * 128 + (kc * 4 + quad) * 16 + l15) * 8);
                oacc[dt] = MFMA16(pf, vf, oacc[dt]);
            }
        }
    }

    float linv[4];
#pragma unroll
    for (int r = 0; r < 4; ++r) linv[r] = 1.f / l4[r];
#pragma unroll
    for (int r = 0; r < 4; ++r) {
        const int n = qt * 64 + wave * 16 + quad * 4 + r;
        if (n < 577) {
            u16* op = aout + ((size_t)b * 577 + n) * 768 + h * 64 + l15;
#pragma unroll
            for (int dt = 0; dt < 4; ++dt)
                op[dt * 16] = f2b(oacc[dt][r] * linv[r]);
        }
    }
}

// ---------------------------------------------------------------------------
// Workspace layout (62,988,288 B total):
//   xb/aout @ 0        (14,180,352)  [xb dead after gemm1; aout overlaps]
//   wqkvT  @ 14,180,352 ( 3,538,944)
//   wprojT @ 17,719,296 ( 1,179,648)
//   qkv    @ 18,898,944 (28,360,704)  [Q,K only; 1536-stride; RoPE applied]
//   VtG    @ 47,259,648 (15,728,640)  [written by gemm1 epilogue, coalesced]
// ---------------------------------------------------------------------------
extern "C" void kernel_launch(void* const* d_in, const int* in_sizes, int n_in,
                              void* d_out, int out_size, void* d_ws, size_t ws_size,
                              hipStream_t stream) {
    const float* x      = (const float*)d_in[0];
    const float* cosp   = (const float*)d_in[1];
    const float* sinp   = (const float*)d_in[2];
    const float* w_qkv  = (const float*)d_in[3];
    const float* b_qkv  = (const float*)d_in[4];
    const float* w_proj = (const float*)d_in[5];
    const float* b_proj = (const float*)d_in[6];
    float* out = (float*)d_out;

    char* ws = (char*)d_ws;
    u16* xb     = (u16*)(ws);
    u16* aout   = (u16*)(ws);              // overlaps xb (dead after gemm1)
    u16* wqkvT  = (u16*)(ws + 14180352);
    u16* wprojT = (u16*)(ws + 17719296);
    u16* qkv    = (u16*)(ws + 18898944);
    u16* VtG    = (u16*)(ws + 47259648);

    f32_to_bf16<<<6924, 256, 0, stream>>>(x, xb, 7090176);
    transpose_f32_bf16<<<dim3(72, 24), 256, 0, stream>>>(w_qkv, wqkvT, 768, 2304);
    transpose_f32_bf16<<<dim3(24, 24), 256, 0, stream>>>(w_proj, wprojT, 768, 768);
    gemm_bt<2><<<dim3(73, 18), 256, 0, stream>>>(xb, wqkvT, b_qkv, qkv,
                                                 cosp, sinp, VtG, 9232, 2304, 768);
    attn2<<<dim3(10, 192), 256, 0, stream>>>(qkv, VtG, aout);
    hipMemsetAsync(out, 0, (size_t)9232 * 768 * 4, stream);
    gemm_bt<1><<<dim3(73, 6, 2), 256, 0, stream>>>(aout, wprojT, b_proj, out,
                                                   nullptr, nullptr, nullptr, 9232, 768, 768);
}

// Round 7
// 300.261 us; speedup vs baseline: 1.4863x; 1.4863x over previous
//
#include <hip/hip_runtime.h>
#include <stdint.h>

typedef unsigned short u16;
typedef __attribute__((ext_vector_type(8))) short bf16x8;
typedef __attribute__((ext_vector_type(4))) float f32x4;

#define MFMA16(a, b, c) __builtin_amdgcn_mfma_f32_16x16x32_bf16((a), (b), (c), 0, 0, 0)

__device__ __forceinline__ float b2f(u16 u) {
    union { unsigned int i; float f; } v; v.i = ((unsigned int)u) << 16; return v.f;
}
__device__ __forceinline__ u16 f2b(float f) {
    union { float f; unsigned int i; } v; v.f = f;
    unsigned int r = v.i + 0x7fffu + ((v.i >> 16) & 1u);
    return (u16)(r >> 16);
}
__device__ __forceinline__ unsigned int pack2(float a, float b) {
    return (unsigned int)f2b(a) | ((unsigned int)f2b(b) << 16);
}

typedef __attribute__((address_space(1))) void gvoid;
typedef __attribute__((address_space(3))) void lvoid;
__device__ __forceinline__ void gld16(const void* g, void* l) {
    __builtin_amdgcn_global_load_lds((gvoid*)(void*)g, (lvoid*)l, 16, 0, 0);
}

// Panel-swizzled block mapping: 8-row-tile panels, col-major inside a panel.
// Keeps A's reuse window ~1.6 MB -> L2-resident (FETCH 139->52 MB, measured R5).
__device__ __forceinline__ void tile_from_bid(int bid, int nTM, int nTN,
                                              int& rt, int& ct) {
    const int PW = 8;
    const int full = nTM / PW;
    const int per = PW * nTN;
    int p = bid / per;
    int pw = PW;
    int rem = bid - p * per;
    if (p >= full) { p = full; rem = bid - full * per; pw = nTM - full * PW; }
    const int c = rem / pw;
    const int r = rem - c * pw;
    rt = p * PW + r;
    ct = c;
}

// ---------------------------------------------------------------------------
// fp32 -> bf16 elementwise convert (n multiple of 4)
// ---------------------------------------------------------------------------
__global__ __launch_bounds__(256) void f32_to_bf16(const float* __restrict__ in,
                                                   u16* __restrict__ out, int n) {
    const int i = (blockIdx.x * 256 + threadIdx.x) * 4;
    if (i + 3 < n) {
        const float4 v = *(const float4*)(in + i);
        ushort4 o;
        o.x = f2b(v.x); o.y = f2b(v.y); o.z = f2b(v.z); o.w = f2b(v.w);
        *(ushort4*)(out + i) = o;
    }
}

// ---------------------------------------------------------------------------
// fused transpose + fp32->bf16: out[C x R](bf16) = in[R x C](f32)^T
// ---------------------------------------------------------------------------
__global__ __launch_bounds__(256) void transpose_f32_bf16(const float* __restrict__ in,
                                                          u16* __restrict__ out,
                                                          int R, int C) {
    __shared__ float tile[32][33];
    const int t = threadIdx.x;
    const int r = t >> 3, c4 = (t & 7) * 4;
    const int ir = blockIdx.y * 32 + r, ic = blockIdx.x * 32 + c4;
    const float4 v = *(const float4*)(in + (size_t)ir * C + ic);
    tile[r][c4 + 0] = v.x; tile[r][c4 + 1] = v.y;
    tile[r][c4 + 2] = v.z; tile[r][c4 + 3] = v.w;
    __syncthreads();
    const int orow = blockIdx.x * 32 + r, ocol = blockIdx.y * 32 + c4;
    ushort4 o;
    o.x = f2b(tile[c4 + 0][r]); o.y = f2b(tile[c4 + 1][r]);
    o.z = f2b(tile[c4 + 2][r]); o.w = f2b(tile[c4 + 3][r]);
    *(ushort4*)(out + (size_t)orow * R + ocol) = o;
}

// ---------------------------------------------------------------------------
// In-place RoPE on the q,k sections of qkv (2304-stride, cols 0..1535), n>=1.
// ---------------------------------------------------------------------------
__global__ __launch_bounds__(256) void rope_qk(u16* __restrict__ qkv,
                                               const float* __restrict__ cosp,
                                               const float* __restrict__ sinp) {
    const int g = blockIdx.x * 256 + threadIdx.x;   // 16*576*192 total
    const int bn = g / 192, ch = g - bn * 192;
    const int b = bn / 576, n = (bn - b * 576) + 1;
    const int col = ch * 8;
    const int d = col & 63;
    u16* p = qkv + ((size_t)b * 577 + n) * 2304 + col;
    const uint4 raw = *(const uint4*)p;
    const float4 c = *(const float4*)(cosp + (size_t)(n - 1) * 32 + (d >> 1));
    const float4 s = *(const float4*)(sinp + (size_t)(n - 1) * 32 + (d >> 1));
    const unsigned int w[4] = {raw.x, raw.y, raw.z, raw.w};
    const float ca[4] = {c.x, c.y, c.z, c.w};
    const float sa[4] = {s.x, s.y, s.z, s.w};
    uint4 o;
    unsigned int* op = (unsigned int*)&o;
#pragma unroll
    for (int j = 0; j < 4; ++j) {
        const float t0 = b2f((u16)(w[j] & 0xffffu));
        const float t1 = b2f((u16)(w[j] >> 16));
        op[j] = pack2(t0 * ca[j] - t1 * sa[j], t0 * sa[j] + t1 * ca[j]);
    }
    *(uint4*)p = o;
}

// ---------------------------------------------------------------------------
// V pre-transpose: VtG[bh][d(64)][n(640 padded, zero-filled)]
// ---------------------------------------------------------------------------
__global__ __launch_bounds__(256) void transpose_v(const u16* __restrict__ qkv,
                                                   u16* __restrict__ VtG) {
    __shared__ u16 tile[32][36];
    const int t = threadIdx.x;
    const int r = t >> 3, c4 = (t & 7) * 4;
    const int bh = blockIdx.z, b = bh / 12, h = bh - b * 12;
    const int n0 = blockIdx.x * 32, d0 = blockIdx.y * 32;
    const int n = n0 + r;
    ushort4 v = {0, 0, 0, 0};
    if (n < 577)
        v = *(const ushort4*)(qkv + ((size_t)b * 577 + n) * 2304 + 1536 + h * 64 + d0 + c4);
    tile[r][c4 + 0] = v.x; tile[r][c4 + 1] = v.y;
    tile[r][c4 + 2] = v.z; tile[r][c4 + 3] = v.w;
    __syncthreads();
    ushort4 o;
    o.x = tile[c4 + 0][r]; o.y = tile[c4 + 1][r];
    o.z = tile[c4 + 2][r]; o.w = tile[c4 + 3][r];
    *(ushort4*)(VtG + ((size_t)bh * 64 + d0 + r) * 640 + n0 + c4) = o;
}

// ---------------------------------------------------------------------------
// C = A(bf16)[M x K] * Bt(bf16)[N x K]^T + bias(f32)[N]
// 128x128 tile, BK=64, 256 threads (4 waves 2x2 over 64x64), global_load_lds.
// MFMA operands UNCONDITIONALLY swapped (D^T fragment: l15 = row, quad*4+r =
// 4 consecutive cols) -> epilogue is 16 packed ushort4/float4 stores per
// thread instead of 64 scalar stores. No branch in K-loop (R6 lesson).
// EPI: 0 = bf16 store (stride N), 1 = f32 store (stride N).
// ---------------------------------------------------------------------------
template <int EPI>
__global__ __launch_bounds__(256) void gemm_bt(const u16* __restrict__ A,
                                               const u16* __restrict__ Bt,
                                               const float* __restrict__ bias,
                                               void* __restrict__ Cv,
                                               int M, int N, int K) {
    __shared__ __align__(16) u16 As[128 * 64];
    __shared__ __align__(16) u16 Bs[128 * 64];

    const int t = threadIdx.x;
    const int lane = t & 63;
    const int wave = t >> 6;
    const int l15 = lane & 15, quad = lane >> 4;
    const int wm = wave >> 1, wn = wave & 1;

    int rt, ct;
    tile_from_bid(blockIdx.y * gridDim.x + blockIdx.x, gridDim.x, gridDim.y, rt, ct);
    const int row0 = rt * 128;
    const int col0 = ct * 128;

    const f32x4 fz = {0.f, 0.f, 0.f, 0.f};
    f32x4 acc[4][4];
#pragma unroll
    for (int i = 0; i < 4; ++i)
#pragma unroll
        for (int j = 0; j < 4; ++j) acc[i][j] = fz;

    const u16* Ap[4]; u16* Al[4];
    const u16* Bp[4]; u16* Bl[4];
#pragma unroll
    for (int n = 0; n < 4; ++n) {
        const int c = t + n * 256;
        const int row = ((c >> 7) << 4) + (c & 15);
        const int kc = (c >> 4) & 7;
        int ar = row0 + row; if (ar > M - 1) ar = M - 1;   // clamp partial M tile
        Ap[n] = A + (size_t)ar * K + kc * 8;
        Al[n] = As + (size_t)c * 8;
        Bp[n] = Bt + (size_t)(col0 + row) * K + kc * 8;    // N % 128 == 0
        Bl[n] = Bs + (size_t)c * 8;
    }

    const int nKT = K >> 6;
    for (int kt = 0; kt < nKT; ++kt) {
        __syncthreads();
        const int kb = kt << 6;
#pragma unroll
        for (int n = 0; n < 4; ++n) gld16(Ap[n] + kb, Al[n]);
#pragma unroll
        for (int n = 0; n < 4; ++n) gld16(Bp[n] + kb, Bl[n]);
        __syncthreads();
#pragma unroll
        for (int kk = 0; kk < 2; ++kk) {
            bf16x8 af[4], bfr[4];
#pragma unroll
            for (int mi = 0; mi < 4; ++mi)
                af[mi] = *(const bf16x8*)(As + ((size_t)((wm * 4 + mi) * 128 + (kk * 4 + quad) * 16 + l15)) * 8);
#pragma unroll
            for (int ni = 0; ni < 4; ++ni)
                bfr[ni] = *(const bf16x8*)(Bs + ((size_t)((wn * 4 + ni) * 128 + (kk * 4 + quad) * 16 + l15)) * 8);
#pragma unroll
            for (int mi = 0; mi < 4; ++mi)
#pragma unroll
                for (int ni = 0; ni < 4; ++ni)
                    acc[mi][ni] = MFMA16(bfr[ni], af[mi], acc[mi][ni]);
        }
    }

    // ---- epilogue: D^T layout -> packed 4-col stores ----
#pragma unroll
    for (int ni = 0; ni < 4; ++ni) {
        const int colb = col0 + wn * 64 + ni * 16 + quad * 4;
        const float4 bv = *(const float4*)(bias + colb);
#pragma unroll
        for (int mi = 0; mi < 4; ++mi) {
            const int row = row0 + wm * 64 + mi * 16 + l15;
            if (row < M) {
                if (EPI == 1) {
                    float4 o;
                    o.x = acc[mi][ni][0] + bv.x; o.y = acc[mi][ni][1] + bv.y;
                    o.z = acc[mi][ni][2] + bv.z; o.w = acc[mi][ni][3] + bv.w;
                    *(float4*)((float*)Cv + (size_t)row * N + colb) = o;
                } else {
                    ushort4 o;
                    o.x = f2b(acc[mi][ni][0] + bv.x); o.y = f2b(acc[mi][ni][1] + bv.y);
                    o.z = f2b(acc[mi][ni][2] + bv.z); o.w = f2b(acc[mi][ni][3] + bv.w);
                    *(ushort4*)((u16*)Cv + (size_t)row * N + colb) = o;
                }
            }
        }
    }
}

// ---------------------------------------------------------------------------
// Flash attention (R3-proven version): block = (64-query tile, bh).
// qkv 2304-stride, RoPE pre-applied; V pre-transposed in VtG[bh][d][n(640)].
// ---------------------------------------------------------------------------
#define PSTR 80

__global__ __launch_bounds__(256) void attn2(const u16* __restrict__ qkv,
                                             const u16* __restrict__ VtG,
                                             u16* __restrict__ aout) {
    __shared__ __align__(16) u16 Ks[64 * 64];
    __shared__ __align__(16) u16 Vs[64 * 64];
    __shared__ __align__(16) u16 Pb[4 * 16 * PSTR];

    const int t = threadIdx.x;
    const int lane = t & 63, wave = t >> 6;
    const int l15 = lane & 15, quad = lane >> 4;
    const int qt = blockIdx.x;          // 0..9
    const int bh = blockIdx.y;          // 0..191
    const int b = bh / 12, h = bh - b * 12;
    const u16* baseQ = qkv + (size_t)b * 577 * 2304 + h * 64;
    const u16* baseK = baseQ + 768;
    const u16* vbase = VtG + (size_t)bh * 64 * 640;

    const int mq = qt * 64 + wave * 16 + l15;
    const int nq = mq < 577 ? mq : 576;
    bf16x8 aq[2];
    aq[0] = *(const bf16x8*)(baseQ + (size_t)nq * 2304 + quad * 8);
    aq[1] = *(const bf16x8*)(baseQ + (size_t)nq * 2304 + 32 + quad * 8);

    const int r15 = t & 15, cc = (t >> 4) & 7, rg0 = t >> 7;
    const int row0 = rg0 * 16 + r15, row1 = row0 + 32;
    u16* kl0 = Ks + t * 8;  u16* kl1 = Ks + (t + 256) * 8;
    u16* vl0 = Vs + t * 8;  u16* vl1 = Vs + (t + 256) * 8;
    const u16* vp0 = vbase + (size_t)row0 * 640 + cc * 8;
    const u16* vp1 = vbase + (size_t)row1 * 640 + cc * 8;

    u16* Pw = Pb + wave * 16 * PSTR;

    f32x4 oacc[4];
    const f32x4 fz = {0.f, 0.f, 0.f, 0.f};
#pragma unroll
    for (int i = 0; i < 4; ++i) oacc[i] = fz;
    float m4[4] = {-1e30f, -1e30f, -1e30f, -1e30f};
    float l4[4] = {0.f, 0.f, 0.f, 0.f};

    for (int kt = 0; kt < 10; ++kt) {
        __syncthreads();
        {
            int n0 = kt * 64 + row0; if (n0 > 576) n0 = 576;
            int n1 = kt * 64 + row1; if (n1 > 576) n1 = 576;
            gld16(baseK + (size_t)n0 * 2304 + cc * 8, kl0);
            gld16(baseK + (size_t)n1 * 2304 + cc * 8, kl1);
            gld16(vp0 + kt * 64, vl0);
            gld16(vp1 + kt * 64, vl1);
        }
        __syncthreads();

        f32x4 sacc[4];
#pragma unroll
        for (int nt = 0; nt < 4; ++nt) {
            sacc[nt] = fz;
#pragma unroll
            for (int kk = 0; kk < 2; ++kk) {
                const bf16x8 bk = *(const bf16x8*)(Ks + (nt * 128 + (kk * 4 + quad) * 16 + l15) * 8);
                sacc[nt] = MFMA16(aq[kk], bk, sacc[nt]);
            }
        }
        float sv[4][4];
#pragma unroll
        for (int nt = 0; nt < 4; ++nt) {
            const int key = kt * 64 + nt * 16 + l15;
            const bool kvalid = key < 577;
#pragma unroll
            for (int r = 0; r < 4; ++r)
                sv[nt][r] = kvalid ? sacc[nt][r] * 0.125f : -1e30f;
        }
        float mt[4];
#pragma unroll
        for (int r = 0; r < 4; ++r) {
            mt[r] = fmaxf(fmaxf(sv[0][r], sv[1][r]), fmaxf(sv[2][r], sv[3][r]));
#pragma unroll
            for (int off = 1; off <= 8; off <<= 1)
                mt[r] = fmaxf(mt[r], __shfl_xor(mt[r], off));
        }
        float alpha[4];
#pragma unroll
        for (int r = 0; r < 4; ++r) {
            const float mnew = fmaxf(m4[r], mt[r]);
            alpha[r] = __expf(m4[r] - mnew);
            m4[r] = mnew;
        }
        float lsum[4] = {0.f, 0.f, 0.f, 0.f};
#pragma unroll
        for (int nt = 0; nt < 4; ++nt) {
#pragma unroll
            for (int r = 0; r < 4; ++r) {
                const float p = __expf(sv[nt][r] - m4[r]);
                lsum[r] += p;
                Pw[(quad * 4 + r) * PSTR + nt * 16 + l15] = f2b(p);
            }
        }
#pragma unroll
        for (int r = 0; r < 4; ++r) {
#pragma unroll
            for (int off = 1; off <= 8; off <<= 1)
                lsum[r] += __shfl_xor(lsum[r], off);
            l4[r] = l4[r] * alpha[r] + lsum[r];
        }
#pragma unroll
        for (int dt = 0; dt < 4; ++dt)
#pragma unroll
            for (int r = 0; r < 4; ++r) oacc[dt][r] *= alpha[r];

        __asm__ __volatile__("s_waitcnt lgkmcnt(0)" ::: "memory");

#pragma unroll
        for (int kc = 0; kc < 2; ++kc) {
            const bf16x8 pf = *(const bf16x8*)(Pw + l15 * PSTR + kc * 32 + quad * 8);
#pragma unroll
            for (int dt = 0; dt < 4; ++dt) {
                const bf16x8 vf = *(const bf16x8*)(Vs + (dt * 128 + (kc * 4 + quad) * 16 + l15) * 8);
                oacc[dt] = MFMA16(pf, vf, oacc[dt]);
            }
        }
    }

    float linv[4];
#pragma unroll
    for (int r = 0; r < 4; ++r) linv[r] = 1.f / l4[r];
#pragma unroll
    for (int r = 0; r < 4; ++r) {
        const int n = qt * 64 + wave * 16 + quad * 4 + r;
        if (n < 577) {
            u16* op = aout + ((size_t)b * 577 + n) * 768 + h * 64 + l15;
#pragma unroll
            for (int dt = 0; dt < 4; ++dt)
                op[dt * 16] = f2b(oacc[dt][r] * linv[r]);
        }
    }
}

// ---------------------------------------------------------------------------
// Workspace (75,620,352 B total, R3 layout):
//   region A [0, 17,719,296): xb (14,180,352) + wqkvT (3,538,944) for GEMM1,
//       then REUSED for VtG (15,728,640) after GEMM1 completes.
//   wprojT @ 17,719,296 | qkv @ 18,898,944 (42,541,056) | aout @ 61,440,000
// ---------------------------------------------------------------------------
extern "C" void kernel_launch(void* const* d_in, const int* in_sizes, int n_in,
                              void* d_out, int out_size, void* d_ws, size_t ws_size,
                              hipStream_t stream) {
    const float* x      = (const float*)d_in[0];
    const float* cosp   = (const float*)d_in[1];
    const float* sinp   = (const float*)d_in[2];
    const float* w_qkv  = (const float*)d_in[3];
    const float* b_qkv  = (const float*)d_in[4];
    const float* w_proj = (const float*)d_in[5];
    const float* b_proj = (const float*)d_in[6];
    float* out = (float*)d_out;

    char* ws = (char*)d_ws;
    u16* xb     = (u16*)(ws);
    u16* wqkvT  = (u16*)(ws + 14180352);
    u16* VtG    = (u16*)(ws);              // reuses xb/wqkvT after gemm1
    u16* wprojT = (u16*)(ws + 17719296);
    u16* qkv    = (u16*)(ws + 18898944);
    u16* aout   = (u16*)(ws + 61440000);

    f32_to_bf16<<<6924, 256, 0, stream>>>(x, xb, 7090176);
    transpose_f32_bf16<<<dim3(72, 24), 256, 0, stream>>>(w_qkv, wqkvT, 768, 2304);
    transpose_f32_bf16<<<dim3(24, 24), 256, 0, stream>>>(w_proj, wprojT, 768, 768);
    gemm_bt<0><<<dim3(73, 18), 256, 0, stream>>>(xb, wqkvT, b_qkv, qkv, 9232, 2304, 768);
    rope_qk<<<6912, 256, 0, stream>>>(qkv, cosp, sinp);
    transpose_v<<<dim3(20, 2, 192), 256, 0, stream>>>(qkv, VtG);
    attn2<<<dim3(10, 192), 256, 0, stream>>>(qkv, VtG, aout);
    gemm_bt<1><<<dim3(73, 6), 256, 0, stream>>>(aout, wprojT, b_proj, out, 9232, 768, 768);
}

// Round 8
// 290.374 us; speedup vs baseline: 1.5369x; 1.0340x over previous
//
#include <hip/hip_runtime.h>
#include <stdint.h>

typedef unsigned short u16;
typedef __attribute__((ext_vector_type(8))) short bf16x8;
typedef __attribute__((ext_vector_type(4))) float f32x4;

#define MFMA16(a, b, c) __builtin_amdgcn_mfma_f32_16x16x32_bf16((a), (b), (c), 0, 0, 0)

__device__ __forceinline__ float b2f(u16 u) {
    union { unsigned int i; float f; } v; v.i = ((unsigned int)u) << 16; return v.f;
}
__device__ __forceinline__ u16 f2b(float f) {
    union { float f; unsigned int i; } v; v.f = f;
    unsigned int r = v.i + 0x7fffu + ((v.i >> 16) & 1u);
    return (u16)(r >> 16);
}

typedef __attribute__((address_space(1))) void gvoid;
typedef __attribute__((address_space(3))) void lvoid;
__device__ __forceinline__ void gld16(const void* g, void* l) {
    __builtin_amdgcn_global_load_lds((gvoid*)(void*)g, (lvoid*)l, 16, 0, 0);
}

// Panel-swizzled block mapping: 8-row-tile panels, col-major inside a panel.
// Keeps A's reuse window ~1.6 MB -> L2-resident (FETCH 139->52 MB, measured R5).
__device__ __forceinline__ void tile_from_bid(int bid, int nTM, int nTN,
                                              int& rt, int& ct) {
    const int PW = 8;
    const int full = nTM / PW;
    const int per = PW * nTN;
    int p = bid / per;
    int pw = PW;
    int rem = bid - p * per;
    if (p >= full) { p = full; rem = bid - full * per; pw = nTM - full * PW; }
    const int c = rem / pw;
    const int r = rem - c * pw;
    rt = p * PW + r;
    ct = c;
}

// ---------------------------------------------------------------------------
// fp32 -> bf16 elementwise convert (n multiple of 4)
// ---------------------------------------------------------------------------
__global__ __launch_bounds__(256) void f32_to_bf16(const float* __restrict__ in,
                                                   u16* __restrict__ out, int n) {
    const int i = (blockIdx.x * 256 + threadIdx.x) * 4;
    if (i + 3 < n) {
        const float4 v = *(const float4*)(in + i);
        ushort4 o;
        o.x = f2b(v.x); o.y = f2b(v.y); o.z = f2b(v.z); o.w = f2b(v.w);
        *(ushort4*)(out + i) = o;
    }
}

// ---------------------------------------------------------------------------
// fused transpose + fp32->bf16: out[C x R](bf16) = in[R x C](f32)^T
// ---------------------------------------------------------------------------
__global__ __launch_bounds__(256) void transpose_f32_bf16(const float* __restrict__ in,
                                                          u16* __restrict__ out,
                                                          int R, int C) {
    __shared__ float tile[32][33];
    const int t = threadIdx.x;
    const int r = t >> 3, c4 = (t & 7) * 4;
    const int ir = blockIdx.y * 32 + r, ic = blockIdx.x * 32 + c4;
    const float4 v = *(const float4*)(in + (size_t)ir * C + ic);
    tile[r][c4 + 0] = v.x; tile[r][c4 + 1] = v.y;
    tile[r][c4 + 2] = v.z; tile[r][c4 + 3] = v.w;
    __syncthreads();
    const int orow = blockIdx.x * 32 + r, ocol = blockIdx.y * 32 + c4;
    ushort4 o;
    o.x = f2b(tile[c4 + 0][r]); o.y = f2b(tile[c4 + 1][r]);
    o.z = f2b(tile[c4 + 2][r]); o.w = f2b(tile[c4 + 3][r]);
    *(ushort4*)(out + (size_t)orow * R + ocol) = o;
}

// ---------------------------------------------------------------------------
// C = A(bf16)[M x K] * Bt(bf16)[N x K]^T + bias(f32)[N]
// 128x128 tile, BK=64, 256 threads (4 waves 2x2 over 64x64), global_load_lds.
// MFMA operands UNCONDITIONALLY swapped (D^T: l15 = row, quad*4+r = 4
// consecutive cols). Single MFMA body — no branch in K-loop (R6 lesson).
// EPI: 0 = bf16 store (stride N); 1 = f32 store (stride N);
//      2 = fused qkv epilogue (block-uniform branch on col0):
//          Q/K tiles: bias + RoPE (pairs are INTRA-LANE in D^T layout)
//              -> packed ushort4 to qkv (stride 1536, Q 0..767 K 768..1535);
//          V tiles: bias -> scalar stores along l15 = 16 consecutive tokens
//              (32B runs) into VtG[bh][d(64)][n(640)].
// ---------------------------------------------------------------------------
template <int EPI>
__global__ __launch_bounds__(256) void gemm_bt(const u16* __restrict__ A,
                                               const u16* __restrict__ Bt,
                                               const float* __restrict__ bias,
                                               void* __restrict__ Cv,
                                               const float* __restrict__ cosp,
                                               const float* __restrict__ sinp,
                                               u16* __restrict__ VtG,
                                               int M, int N, int K) {
    __shared__ __align__(16) u16 As[128 * 64];
    __shared__ __align__(16) u16 Bs[128 * 64];

    const int t = threadIdx.x;
    const int lane = t & 63;
    const int wave = t >> 6;
    const int l15 = lane & 15, quad = lane >> 4;
    const int wm = wave >> 1, wn = wave & 1;

    int rt, ct;
    tile_from_bid(blockIdx.y * gridDim.x + blockIdx.x, gridDim.x, gridDim.y, rt, ct);
    const int row0 = rt * 128;
    const int col0 = ct * 128;

    const f32x4 fz = {0.f, 0.f, 0.f, 0.f};
    f32x4 acc[4][4];
#pragma unroll
    for (int i = 0; i < 4; ++i)
#pragma unroll
        for (int j = 0; j < 4; ++j) acc[i][j] = fz;

    const u16* Ap[4]; u16* Al[4];
    const u16* Bp[4]; u16* Bl[4];
#pragma unroll
    for (int n = 0; n < 4; ++n) {
        const int c = t + n * 256;
        const int row = ((c >> 7) << 4) + (c & 15);
        const int kc = (c >> 4) & 7;
        int ar = row0 + row; if (ar > M - 1) ar = M - 1;   // clamp partial M tile
        Ap[n] = A + (size_t)ar * K + kc * 8;
        Al[n] = As + (size_t)c * 8;
        Bp[n] = Bt + (size_t)(col0 + row) * K + kc * 8;    // N % 128 == 0
        Bl[n] = Bs + (size_t)c * 8;
    }

    const int nKT = K >> 6;
    for (int kt = 0; kt < nKT; ++kt) {
        __syncthreads();
        const int kb = kt << 6;
#pragma unroll
        for (int n = 0; n < 4; ++n) gld16(Ap[n] + kb, Al[n]);
#pragma unroll
        for (int n = 0; n < 4; ++n) gld16(Bp[n] + kb, Bl[n]);
        __syncthreads();
#pragma unroll
        for (int kk = 0; kk < 2; ++kk) {
            bf16x8 af[4], bfr[4];
#pragma unroll
            for (int mi = 0; mi < 4; ++mi)
                af[mi] = *(const bf16x8*)(As + ((size_t)((wm * 4 + mi) * 128 + (kk * 4 + quad) * 16 + l15)) * 8);
#pragma unroll
            for (int ni = 0; ni < 4; ++ni)
                bfr[ni] = *(const bf16x8*)(Bs + ((size_t)((wn * 4 + ni) * 128 + (kk * 4 + quad) * 16 + l15)) * 8);
#pragma unroll
            for (int mi = 0; mi < 4; ++mi)
#pragma unroll
                for (int ni = 0; ni < 4; ++ni)
                    acc[mi][ni] = MFMA16(bfr[ni], af[mi], acc[mi][ni]);
        }
    }

    // ---- epilogue (D^T layout: row = ...+l15, cols = colb..colb+3) ----
    if (EPI == 2) {
        if (col0 >= 1536) {
            // V tiles -> VtG[bh][d][n], stores contiguous along l15 (token n)
#pragma unroll
            for (int mi = 0; mi < 4; ++mi) {
                const int row = row0 + wm * 64 + mi * 16 + l15;
                if (row < M) {
                    const int bb = row / 577, n = row - bb * 577;
                    u16* vdst = VtG + (size_t)bb * 491520 + n;   // 12*64*640
#pragma unroll
                    for (int ni = 0; ni < 4; ++ni) {
                        const int colb = col0 + wn * 64 + ni * 16 + quad * 4;
                        const float4 bv = *(const float4*)(bias + colb);
#pragma unroll
                        for (int r = 0; r < 4; ++r) {
                            const int cv = colb + r - 1536;
                            vdst[(size_t)(cv >> 6) * 40960 + (cv & 63) * 640] =
                                f2b(acc[mi][ni][r] + ((const float*)&bv)[r]);
                        }
                    }
                }
            }
        } else {
            // Q/K tiles: bias + RoPE (intra-lane pairs) -> 1536-stride qkv
#pragma unroll
            for (int mi = 0; mi < 4; ++mi) {
                const int row = row0 + wm * 64 + mi * 16 + l15;
                if (row < M) {
                    const int bb = row / 577, n = row - bb * 577;
                    const bool hr = (n >= 1);
                    const float* cb = cosp + (size_t)(hr ? (n - 1) : 0) * 32;
                    const float* sb = sinp + (size_t)(hr ? (n - 1) : 0) * 32;
                    u16* outp = (u16*)Cv + (size_t)row * 1536;
#pragma unroll
                    for (int ni = 0; ni < 4; ++ni) {
                        const int colb = col0 + wn * 64 + ni * 16 + quad * 4;
                        const float4 bv = *(const float4*)(bias + colb);
                        const int pi = (colb & 63) >> 1;           // even
                        float2 c = *(const float2*)(cb + pi);
                        float2 s = *(const float2*)(sb + pi);
                        if (!hr) { c.x = 1.f; c.y = 1.f; s.x = 0.f; s.y = 0.f; }
                        const float v0 = acc[mi][ni][0] + bv.x;
                        const float v1 = acc[mi][ni][1] + bv.y;
                        const float v2 = acc[mi][ni][2] + bv.z;
                        const float v3 = acc[mi][ni][3] + bv.w;
                        ushort4 o;
                        o.x = f2b(v0 * c.x - v1 * s.x);
                        o.y = f2b(v0 * s.x + v1 * c.x);
                        o.z = f2b(v2 * c.y - v3 * s.y);
                        o.w = f2b(v2 * s.y + v3 * c.y);
                        *(ushort4*)(outp + colb) = o;
                    }
                }
            }
        }
    } else {
#pragma unroll
        for (int ni = 0; ni < 4; ++ni) {
            const int colb = col0 + wn * 64 + ni * 16 + quad * 4;
            const float4 bv = *(const float4*)(bias + colb);
#pragma unroll
            for (int mi = 0; mi < 4; ++mi) {
                const int row = row0 + wm * 64 + mi * 16 + l15;
                if (row < M) {
                    if (EPI == 1) {
                        float4 o;
                        o.x = acc[mi][ni][0] + bv.x; o.y = acc[mi][ni][1] + bv.y;
                        o.z = acc[mi][ni][2] + bv.z; o.w = acc[mi][ni][3] + bv.w;
                        *(float4*)((float*)Cv + (size_t)row * N + colb) = o;
                    } else {
                        ushort4 o;
                        o.x = f2b(acc[mi][ni][0] + bv.x); o.y = f2b(acc[mi][ni][1] + bv.y);
                        o.z = f2b(acc[mi][ni][2] + bv.z); o.w = f2b(acc[mi][ni][3] + bv.w);
                        *(ushort4*)((u16*)Cv + (size_t)row * N + colb) = o;
                    }
                }
            }
        }
    }
}

// ---------------------------------------------------------------------------
// Flash attention: block = (64-query tile, bh). Online softmax, 64-key tiles.
// qkv 1536-stride (Q 0..767, K 768..1535), RoPE pre-applied by gemm1 epilogue;
// V in VtG[bh][d][n(640)] (tail keys carry poison but are masked via p=0,
// and bf16 poison 0xAAAA is finite). PSTR=72 -> 2-way LDS banks (free).
// ---------------------------------------------------------------------------
#define PSTR 72

__global__ __launch_bounds__(256) void attn2(const u16* __restrict__ qkv,
                                             const u16* __restrict__ VtG,
                                             u16* __restrict__ aout) {
    __shared__ __align__(16) u16 Ks[64 * 64];
    __shared__ __align__(16) u16 Vs[64 * 64];
    __shared__ __align__(16) u16 Pb[4 * 16 * PSTR];

    const int t = threadIdx.x;
    const int lane = t & 63, wave = t >> 6;
    const int l15 = lane & 15, quad = lane >> 4;
    const int qt = blockIdx.x;          // 0..9
    const int bh = blockIdx.y;          // 0..191
    const int b = bh / 12, h = bh - b * 12;
    const u16* baseQ = qkv + (size_t)b * 577 * 1536 + h * 64;
    const u16* baseK = baseQ + 768;
    const u16* vbase = VtG + (size_t)bh * 64 * 640;

    const int mq = qt * 64 + wave * 16 + l15;
    const int nq = mq < 577 ? mq : 576;
    bf16x8 aq[2];
    aq[0] = *(const bf16x8*)(baseQ + (size_t)nq * 1536 + quad * 8);
    aq[1] = *(const bf16x8*)(baseQ + (size_t)nq * 1536 + 32 + quad * 8);

    const int r15 = t & 15, cc = (t >> 4) & 7, rg0 = t >> 7;
    const int row0 = rg0 * 16 + r15, row1 = row0 + 32;
    u16* kl0 = Ks + t * 8;  u16* kl1 = Ks + (t + 256) * 8;
    u16* vl0 = Vs + t * 8;  u16* vl1 = Vs + (t + 256) * 8;
    const u16* vp0 = vbase + (size_t)row0 * 640 + cc * 8;
    const u16* vp1 = vbase + (size_t)row1 * 640 + cc * 8;

    u16* Pw = Pb + wave * 16 * PSTR;

    f32x4 oacc[4];
    const f32x4 fz = {0.f, 0.f, 0.f, 0.f};
#pragma unroll
    for (int i = 0; i < 4; ++i) oacc[i] = fz;
    float m4[4] = {-1e30f, -1e30f, -1e30f, -1e30f};
    float l4[4] = {0.f, 0.f, 0.f, 0.f};

    for (int kt = 0; kt < 10; ++kt) {
        __syncthreads();
        {
            int n0 = kt * 64 + row0; if (n0 > 576) n0 = 576;
            int n1 = kt * 64 + row1; if (n1 > 576) n1 = 576;
            gld16(baseK + (size_t)n0 * 1536 + cc * 8, kl0);
            gld16(baseK + (size_t)n1 * 1536 + cc * 8, kl1);
            gld16(vp0 + kt * 64, vl0);
            gld16(vp1 + kt * 64, vl1);
        }
        __syncthreads();

        f32x4 sacc[4];
#pragma unroll
        for (int nt = 0; nt < 4; ++nt) {
            sacc[nt] = fz;
#pragma unroll
            for (int kk = 0; kk < 2; ++kk) {
                const bf16x8 bk = *(const bf16x8*)(Ks + (nt * 128 + (kk * 4 + quad) * 16 + l15) * 8);
                sacc[nt] = MFMA16(aq[kk], bk, sacc[nt]);
            }
        }
        float sv[4][4];
#pragma unroll
        for (int nt = 0; nt < 4; ++nt) {
            const int key = kt * 64 + nt * 16 + l15;
            const bool kvalid = key < 577;
#pragma unroll
            for (int r = 0; r < 4; ++r)
                sv[nt][r] = kvalid ? sacc[nt][r] * 0.125f : -1e30f;
        }
        float mt[4];
#pragma unroll
        for (int r = 0; r < 4; ++r) {
            mt[r] = fmaxf(fmaxf(sv[0][r], sv[1][r]), fmaxf(sv[2][r], sv[3][r]));
#pragma unroll
            for (int off = 1; off <= 8; off <<= 1)
                mt[r] = fmaxf(mt[r], __shfl_xor(mt[r], off));
        }
        float alpha[4];
#pragma unroll
        for (int r = 0; r < 4; ++r) {
            const float mnew = fmaxf(m4[r], mt[r]);
            alpha[r] = __expf(m4[r] - mnew);
            m4[r] = mnew;
        }
        float lsum[4] = {0.f, 0.f, 0.f, 0.f};
#pragma unroll
        for (int nt = 0; nt < 4; ++nt) {
#pragma unroll
            for (int r = 0; r < 4; ++r) {
                const float p = __expf(sv[nt][r] - m4[r]);
                lsum[r] += p;
                Pw[(quad * 4 + r) * PSTR + nt * 16 + l15] = f2b(p);
            }
        }
#pragma unroll
        for (int r = 0; r < 4; ++r) {
#pragma unroll
            for (int off = 1; off <= 8; off <<= 1)
                lsum[r] += __shfl_xor(lsum[r], off);
            l4[r] = l4[r] * alpha[r] + lsum[r];
        }
#pragma unroll
        for (int dt = 0; dt < 4; ++dt)
#pragma unroll
            for (int r = 0; r < 4; ++r) oacc[dt][r] *= alpha[r];

        __asm__ __volatile__("s_waitcnt lgkmcnt(0)" ::: "memory");

#pragma unroll
        for (int kc = 0; kc < 2; ++kc) {
            const bf16x8 pf = *(const bf16x8*)(Pw + l15 * PSTR + kc * 32 + quad * 8);
#pragma unroll
            for (int dt = 0; dt < 4; ++dt) {
                const bf16x8 vf = *(const bf16x8*)(Vs + (dt * 128 + (kc * 4 + quad) * 16 + l15) * 8);
                oacc[dt] = MFMA16(pf, vf, oacc[dt]);
            }
        }
    }

    float linv[4];
#pragma unroll
    for (int r = 0; r < 4; ++r) linv[r] = 1.f / l4[r];
#pragma unroll
    for (int r = 0; r < 4; ++r) {
        const int n = qt * 64 + wave * 16 + quad * 4 + r;
        if (n < 577) {
            u16* op = aout + ((size_t)b * 577 + n) * 768 + h * 64 + l15;
#pragma unroll
            for (int dt = 0; dt < 4; ++dt)
                op[dt * 16] = f2b(oacc[dt][r] * linv[r]);
        }
    }
}

// ---------------------------------------------------------------------------
// Workspace layout (62,988,288 B total):
//   xb/aout @ 0        (14,180,352)  [xb dead after gemm1; aout overlaps]
//   wqkvT  @ 14,180,352 ( 3,538,944)
//   wprojT @ 17,719,296 ( 1,179,648)
//   qkv    @ 18,898,944 (28,360,704)  [Q,K only; 1536-stride; RoPE applied]
//   VtG    @ 47,259,648 (15,728,640)  [written by gemm1 epilogue]
// ---------------------------------------------------------------------------
extern "C" void kernel_launch(void* const* d_in, const int* in_sizes, int n_in,
                              void* d_out, int out_size, void* d_ws, size_t ws_size,
                              hipStream_t stream) {
    const float* x      = (const float*)d_in[0];
    const float* cosp   = (const float*)d_in[1];
    const float* sinp   = (const float*)d_in[2];
    const float* w_qkv  = (const float*)d_in[3];
    const float* b_qkv  = (const float*)d_in[4];
    const float* w_proj = (const float*)d_in[5];
    const float* b_proj = (const float*)d_in[6];
    float* out = (float*)d_out;

    char* ws = (char*)d_ws;
    u16* xb     = (u16*)(ws);
    u16* aout   = (u16*)(ws);              // overlaps xb (dead after gemm1)
    u16* wqkvT  = (u16*)(ws + 14180352);
    u16* wprojT = (u16*)(ws + 17719296);
    u16* qkv    = (u16*)(ws + 18898944);
    u16* VtG    = (u16*)(ws + 47259648);

    f32_to_bf16<<<6924, 256, 0, stream>>>(x, xb, 7090176);
    transpose_f32_bf16<<<dim3(72, 24), 256, 0, stream>>>(w_qkv, wqkvT, 768, 2304);
    transpose_f32_bf16<<<dim3(24, 24), 256, 0, stream>>>(w_proj, wprojT, 768, 768);
    gemm_bt<2><<<dim3(73, 18), 256, 0, stream>>>(xb, wqkvT, b_qkv, qkv,
                                                 cosp, sinp, VtG, 9232, 2304, 768);
    attn2<<<dim3(10, 192), 256, 0, stream>>>(qkv, VtG, aout);
    gemm_bt<1><<<dim3(73, 6), 256, 0, stream>>>(aout, wprojT, b_proj, out,
                                                nullptr, nullptr, nullptr, 9232, 768, 768);
}

// Round 9
// 287.188 us; speedup vs baseline: 1.5540x; 1.0111x over previous
//
#include <hip/hip_runtime.h>
#include <stdint.h>

typedef unsigned short u16;
typedef __attribute__((ext_vector_type(8))) short bf16x8;
typedef __attribute__((ext_vector_type(4))) float f32x4;

#define MFMA16(a, b, c) __builtin_amdgcn_mfma_f32_16x16x32_bf16((a), (b), (c), 0, 0, 0)

__device__ __forceinline__ float b2f(u16 u) {
    union { unsigned int i; float f; } v; v.i = ((unsigned int)u) << 16; return v.f;
}
__device__ __forceinline__ u16 f2b(float f) {
    union { float f; unsigned int i; } v; v.f = f;
    unsigned int r = v.i + 0x7fffu + ((v.i >> 16) & 1u);
    return (u16)(r >> 16);
}

typedef __attribute__((address_space(1))) void gvoid;
typedef __attribute__((address_space(3))) void lvoid;
__device__ __forceinline__ void gld16(const void* g, void* l) {
    __builtin_amdgcn_global_load_lds((gvoid*)(void*)g, (lvoid*)l, 16, 0, 0);
}

// Panel-swizzled block mapping: 8-row-tile panels, col-major inside a panel.
// Keeps A's reuse window ~1.6 MB -> L2-resident (FETCH 139->52 MB, measured R5).
__device__ __forceinline__ void tile_from_bid(int bid, int nTM, int nTN,
                                              int& rt, int& ct) {
    const int PW = 8;
    const int full = nTM / PW;
    const int per = PW * nTN;
    int p = bid / per;
    int pw = PW;
    int rem = bid - p * per;
    if (p >= full) { p = full; rem = bid - full * per; pw = nTM - full * PW; }
    const int c = rem / pw;
    const int r = rem - c * pw;
    rt = p * PW + r;
    ct = c;
}

// ---------------------------------------------------------------------------
// fp32 -> bf16 elementwise convert (n multiple of 4)
// ---------------------------------------------------------------------------
__global__ __launch_bounds__(256) void f32_to_bf16(const float* __restrict__ in,
                                                   u16* __restrict__ out, int n) {
    const int i = (blockIdx.x * 256 + threadIdx.x) * 4;
    if (i + 3 < n) {
        const float4 v = *(const float4*)(in + i);
        ushort4 o;
        o.x = f2b(v.x); o.y = f2b(v.y); o.z = f2b(v.z); o.w = f2b(v.w);
        *(ushort4*)(out + i) = o;
    }
}

// ---------------------------------------------------------------------------
// merged transpose + fp32->bf16 for BOTH weights (one launch):
//   blockIdx.x <  72: w_qkv (768 x 2304) -> wqkvT (2304 x 768)
//   blockIdx.x >= 72: w_proj (768 x 768) -> wprojT (768 x 768)
// ---------------------------------------------------------------------------
__global__ __launch_bounds__(256) void transpose_w(const float* __restrict__ wqkv,
                                                   const float* __restrict__ wproj,
                                                   u16* __restrict__ outQ,
                                                   u16* __restrict__ outP) {
    __shared__ float tile[32][33];
    int bx = blockIdx.x;
    const float* in; u16* out; int C;
    if (bx < 72) { in = wqkv; out = outQ; C = 2304; }
    else         { bx -= 72; in = wproj; out = outP; C = 768; }
    const int R = 768;
    const int t = threadIdx.x;
    const int r = t >> 3, c4 = (t & 7) * 4;
    const int ir = blockIdx.y * 32 + r, ic = bx * 32 + c4;
    const float4 v = *(const float4*)(in + (size_t)ir * C + ic);
    tile[r][c4 + 0] = v.x; tile[r][c4 + 1] = v.y;
    tile[r][c4 + 2] = v.z; tile[r][c4 + 3] = v.w;
    __syncthreads();
    const int orow = bx * 32 + r, ocol = blockIdx.y * 32 + c4;
    ushort4 o;
    o.x = f2b(tile[c4 + 0][r]); o.y = f2b(tile[c4 + 1][r]);
    o.z = f2b(tile[c4 + 2][r]); o.w = f2b(tile[c4 + 3][r]);
    *(ushort4*)(out + (size_t)orow * R + ocol) = o;
}

// ---------------------------------------------------------------------------
// C = A(bf16)[M x K] * Bt(bf16)[N x K]^T + bias(f32)[N]
// 128x128 tile, BK=64, **512 threads = 8 waves in 2x4** (each wave 64x32:
// acc[4][2] = 32 AGPRs -> ~5 waves/SIMD, ~2 blocks/CU co-resident; more
// waves cover each barrier's vmcnt drain). global_load_lds staging, chunked
// LDS (chunk c -> row ((c>>7)<<4)+(c&15), kc (c>>4)&7), 2 A + 2 B chunks
// per thread. MFMA operands swapped (D^T: l15 = row, quad*4+r = 4 cols).
// EPI: 1 = f32 store (stride N);
//      2 = fused qkv epilogue (block-uniform branch on col0):
//          Q/K tiles: bias + RoPE (intra-lane pairs) -> qkv (stride 1536);
//          V tiles: bias -> stores contiguous along l15 into VtG[bh][d][n].
// ---------------------------------------------------------------------------
template <int EPI>
__global__ __launch_bounds__(512) void gemm_bt(const u16* __restrict__ A,
                                               const u16* __restrict__ Bt,
                                               const float* __restrict__ bias,
                                               void* __restrict__ Cv,
                                               const float* __restrict__ cosp,
                                               const float* __restrict__ sinp,
                                               u16* __restrict__ VtG,
                                               int M, int N, int K) {
    __shared__ __align__(16) u16 As[128 * 64];
    __shared__ __align__(16) u16 Bs[128 * 64];

    const int t = threadIdx.x;
    const int lane = t & 63;
    const int wave = t >> 6;              // 0..7
    const int l15 = lane & 15, quad = lane >> 4;
    const int wm = wave >> 2;             // 0..1 (64 rows each)
    const int wn = wave & 3;              // 0..3 (32 cols each)

    int rt, ct;
    tile_from_bid(blockIdx.y * gridDim.x + blockIdx.x, gridDim.x, gridDim.y, rt, ct);
    const int row0 = rt * 128;
    const int col0 = ct * 128;

    const f32x4 fz = {0.f, 0.f, 0.f, 0.f};
    f32x4 acc[4][2];
#pragma unroll
    for (int i = 0; i < 4; ++i)
#pragma unroll
        for (int j = 0; j < 2; ++j) acc[i][j] = fz;

    const u16* Ap[2]; u16* Al[2];
    const u16* Bp[2]; u16* Bl[2];
#pragma unroll
    for (int n = 0; n < 2; ++n) {
        const int c = t + n * 512;
        const int row = ((c >> 7) << 4) + (c & 15);
        const int kc = (c >> 4) & 7;
        int ar = row0 + row; if (ar > M - 1) ar = M - 1;   // clamp partial M tile
        Ap[n] = A + (size_t)ar * K + kc * 8;
        Al[n] = As + (size_t)c * 8;
        Bp[n] = Bt + (size_t)(col0 + row) * K + kc * 8;    // N % 128 == 0
        Bl[n] = Bs + (size_t)c * 8;
    }

    const int nKT = K >> 6;
    for (int kt = 0; kt < nKT; ++kt) {
        __syncthreads();
        const int kb = kt << 6;
#pragma unroll
        for (int n = 0; n < 2; ++n) gld16(Ap[n] + kb, Al[n]);
#pragma unroll
        for (int n = 0; n < 2; ++n) gld16(Bp[n] + kb, Bl[n]);
        __syncthreads();
#pragma unroll
        for (int kk = 0; kk < 2; ++kk) {
            bf16x8 af[4], bfr[2];
#pragma unroll
            for (int mi = 0; mi < 4; ++mi)
                af[mi] = *(const bf16x8*)(As + ((size_t)((wm * 4 + mi) * 128 + (kk * 4 + quad) * 16 + l15)) * 8);
#pragma unroll
            for (int ni = 0; ni < 2; ++ni)
                bfr[ni] = *(const bf16x8*)(Bs + ((size_t)((wn * 2 + ni) * 128 + (kk * 4 + quad) * 16 + l15)) * 8);
#pragma unroll
            for (int mi = 0; mi < 4; ++mi)
#pragma unroll
                for (int ni = 0; ni < 2; ++ni)
                    acc[mi][ni] = MFMA16(bfr[ni], af[mi], acc[mi][ni]);
        }
    }

    // ---- epilogue (D^T layout: row = ...+l15, cols = colb..colb+3) ----
    if (EPI == 2) {
        if (col0 >= 1536) {
            // V tiles -> VtG[bh][d][n], stores contiguous along l15 (token n)
#pragma unroll
            for (int mi = 0; mi < 4; ++mi) {
                const int row = row0 + wm * 64 + mi * 16 + l15;
                if (row < M) {
                    const int bb = row / 577, n = row - bb * 577;
                    u16* vdst = VtG + (size_t)bb * 491520 + n;   // 12*64*640
#pragma unroll
                    for (int ni = 0; ni < 2; ++ni) {
                        const int colb = col0 + wn * 32 + ni * 16 + quad * 4;
                        const float4 bv = *(const float4*)(bias + colb);
#pragma unroll
                        for (int r = 0; r < 4; ++r) {
                            const int cv = colb + r - 1536;
                            vdst[(size_t)(cv >> 6) * 40960 + (cv & 63) * 640] =
                                f2b(acc[mi][ni][r] + ((const float*)&bv)[r]);
                        }
                    }
                }
            }
        } else {
            // Q/K tiles: bias + RoPE (intra-lane pairs) -> 1536-stride qkv
#pragma unroll
            for (int mi = 0; mi < 4; ++mi) {
                const int row = row0 + wm * 64 + mi * 16 + l15;
                if (row < M) {
                    const int bb = row / 577, n = row - bb * 577;
                    const bool hr = (n >= 1);
                    const float* cb = cosp + (size_t)(hr ? (n - 1) : 0) * 32;
                    const float* sb = sinp + (size_t)(hr ? (n - 1) : 0) * 32;
                    u16* outp = (u16*)Cv + (size_t)row * 1536;
#pragma unroll
                    for (int ni = 0; ni < 2; ++ni) {
                        const int colb = col0 + wn * 32 + ni * 16 + quad * 4;
                        const float4 bv = *(const float4*)(bias + colb);
                        const int pi = (colb & 63) >> 1;           // even
                        float2 c = *(const float2*)(cb + pi);
                        float2 s = *(const float2*)(sb + pi);
                        if (!hr) { c.x = 1.f; c.y = 1.f; s.x = 0.f; s.y = 0.f; }
                        const float v0 = acc[mi][ni][0] + bv.x;
                        const float v1 = acc[mi][ni][1] + bv.y;
                        const float v2 = acc[mi][ni][2] + bv.z;
                        const float v3 = acc[mi][ni][3] + bv.w;
                        ushort4 o;
                        o.x = f2b(v0 * c.x - v1 * s.x);
                        o.y = f2b(v0 * s.x + v1 * c.x);
                        o.z = f2b(v2 * c.y - v3 * s.y);
                        o.w = f2b(v2 * s.y + v3 * c.y);
                        *(ushort4*)(outp + colb) = o;
                    }
                }
            }
        }
    } else {
#pragma unroll
        for (int ni = 0; ni < 2; ++ni) {
            const int colb = col0 + wn * 32 + ni * 16 + quad * 4;
            const float4 bv = *(const float4*)(bias + colb);
#pragma unroll
            for (int mi = 0; mi < 4; ++mi) {
                const int row = row0 + wm * 64 + mi * 16 + l15;
                if (row < M) {
                    float4 o;
                    o.x = acc[mi][ni][0] + bv.x; o.y = acc[mi][ni][1] + bv.y;
                    o.z = acc[mi][ni][2] + bv.z; o.w = acc[mi][ni][3] + bv.w;
                    *(float4*)((float*)Cv + (size_t)row * N + colb) = o;
                }
            }
        }
    }
}

// ---------------------------------------------------------------------------
// Flash attention (unchanged from R8): block = (64-query tile, bh).
// qkv 1536-stride (Q 0..767, K 768..1535), RoPE pre-applied by gemm1;
// V in VtG[bh][d][n(640)] (tail keys masked via p=0). PSTR=72.
// ---------------------------------------------------------------------------
#define PSTR 72

__global__ __launch_bounds__(256) void attn2(const u16* __restrict__ qkv,
                                             const u16* __restrict__ VtG,
                                             u16* __restrict__ aout) {
    __shared__ __align__(16) u16 Ks[64 * 64];
    __shared__ __align__(16) u16 Vs[64 * 64];
    __shared__ __align__(16) u16 Pb[4 * 16 * PSTR];

    const int t = threadIdx.x;
    const int lane = t & 63, wave = t >> 6;
    const int l15 = lane & 15, quad = lane >> 4;
    const int qt = blockIdx.x;          // 0..9
    const int bh = blockIdx.y;          // 0..191
    const int b = bh / 12, h = bh - b * 12;
    const u16* baseQ = qkv + (size_t)b * 577 * 1536 + h * 64;
    const u16* baseK = baseQ + 768;
    const u16* vbase = VtG + (size_t)bh * 64 * 640;

    const int mq = qt * 64 + wave * 16 + l15;
    const int nq = mq < 577 ? mq : 576;
    bf16x8 aq[2];
    aq[0] = *(const bf16x8*)(baseQ + (size_t)nq * 1536 + quad * 8);
    aq[1] = *(const bf16x8*)(baseQ + (size_t)nq * 1536 + 32 + quad * 8);

    const int r15 = t & 15, cc = (t >> 4) & 7, rg0 = t >> 7;
    const int row0 = rg0 * 16 + r15, row1 = row0 + 32;
    u16* kl0 = Ks + t * 8;  u16* kl1 = Ks + (t + 256) * 8;
    u16* vl0 = Vs + t * 8;  u16* vl1 = Vs + (t + 256) * 8;
    const u16* vp0 = vbase + (size_t)row0 * 640 + cc * 8;
    const u16* vp1 = vbase + (size_t)row1 * 640 + cc * 8;

    u16* Pw = Pb + wave * 16 * PSTR;

    f32x4 oacc[4];
    const f32x4 fz = {0.f, 0.f, 0.f, 0.f};
#pragma unroll
    for (int i = 0; i < 4; ++i) oacc[i] = fz;
    float m4[4] = {-1e30f, -1e30f, -1e30f, -1e30f};
    float l4[4] = {0.f, 0.f, 0.f, 0.f};

    for (int kt = 0; kt < 10; ++kt) {
        __syncthreads();
        {
            int n0 = kt * 64 + row0; if (n0 > 576) n0 = 576;
            int n1 = kt * 64 + row1; if (n1 > 576) n1 = 576;
            gld16(baseK + (size_t)n0 * 1536 + cc * 8, kl0);
            gld16(baseK + (size_t)n1 * 1536 + cc * 8, kl1);
            gld16(vp0 + kt * 64, vl0);
            gld16(vp1 + kt * 64, vl1);
        }
        __syncthreads();

        f32x4 sacc[4];
#pragma unroll
        for (int nt = 0; nt < 4; ++nt) {
            sacc[nt] = fz;
#pragma unroll
            for (int kk = 0; kk < 2; ++kk) {
                const bf16x8 bk = *(const bf16x8*)(Ks + (nt * 128 + (kk * 4 + quad) * 16 + l15) * 8);
                sacc[nt] = MFMA16(aq[kk], bk, sacc[nt]);
            }
        }
        float sv[4][4];
#pragma unroll
        for (int nt = 0; nt < 4; ++nt) {
            const int key = kt * 64 + nt * 16 + l15;
            const bool kvalid = key < 577;
#pragma unroll
            for (int r = 0; r < 4; ++r)
                sv[nt][r] = kvalid ? sacc[nt][r] * 0.125f : -1e30f;
        }
        float mt[4];
#pragma unroll
        for (int r = 0; r < 4; ++r) {
            mt[r] = fmaxf(fmaxf(sv[0][r], sv[1][r]), fmaxf(sv[2][r], sv[3][r]));
#pragma unroll
            for (int off = 1; off <= 8; off <<= 1)
                mt[r] = fmaxf(mt[r], __shfl_xor(mt[r], off));
        }
        float alpha[4];
#pragma unroll
        for (int r = 0; r < 4; ++r) {
            const float mnew = fmaxf(m4[r], mt[r]);
            alpha[r] = __expf(m4[r] - mnew);
            m4[r] = mnew;
        }
        float lsum[4] = {0.f, 0.f, 0.f, 0.f};
#pragma unroll
        for (int nt = 0; nt < 4; ++nt) {
#pragma unroll
            for (int r = 0; r < 4; ++r) {
                const float p = __expf(sv[nt][r] - m4[r]);
                lsum[r] += p;
                Pw[(quad * 4 + r) * PSTR + nt * 16 + l15] = f2b(p);
            }
        }
#pragma unroll
        for (int r = 0; r < 4; ++r) {
#pragma unroll
            for (int off = 1; off <= 8; off <<= 1)
                lsum[r] += __shfl_xor(lsum[r], off);
            l4[r] = l4[r] * alpha[r] + lsum[r];
        }
#pragma unroll
        for (int dt = 0; dt < 4; ++dt)
#pragma unroll
            for (int r = 0; r < 4; ++r) oacc[dt][r] *= alpha[r];

        __asm__ __volatile__("s_waitcnt lgkmcnt(0)" ::: "memory");

#pragma unroll
        for (int kc = 0; kc < 2; ++kc) {
            const bf16x8 pf = *(const bf16x8*)(Pw + l15 * PSTR + kc * 32 + quad * 8);
#pragma unroll
            for (int dt = 0; dt < 4; ++dt) {
                const bf16x8 vf = *(const bf16x8*)(Vs + (dt * 128 + (kc * 4 + quad) * 16 + l15) * 8);
                oacc[dt] = MFMA16(pf, vf, oacc[dt]);
            }
        }
    }

    float linv[4];
#pragma unroll
    for (int r = 0; r < 4; ++r) linv[r] = 1.f / l4[r];
#pragma unroll
    for (int r = 0; r < 4; ++r) {
        const int n = qt * 64 + wave * 16 + quad * 4 + r;
        if (n < 577) {
            u16* op = aout + ((size_t)b * 577 + n) * 768 + h * 64 + l15;
#pragma unroll
            for (int dt = 0; dt < 4; ++dt)
                op[dt * 16] = f2b(oacc[dt][r] * linv[r]);
        }
    }
}

// ---------------------------------------------------------------------------
// Workspace layout (62,988,288 B total):
//   xb/aout @ 0        (14,180,352)  [xb dead after gemm1; aout overlaps]
//   wqkvT  @ 14,180,352 ( 3,538,944)
//   wprojT @ 17,719,296 ( 1,179,648)
//   qkv    @ 18,898,944 (28,360,704)  [Q,K only; 1536-stride; RoPE applied]
//   VtG    @ 47,259,648 (15,728,640)  [written by gemm1 epilogue]
// ---------------------------------------------------------------------------
extern "C" void kernel_launch(void* const* d_in, const int* in_sizes, int n_in,
                              void* d_out, int out_size, void* d_ws, size_t ws_size,
                              hipStream_t stream) {
    const float* x      = (const float*)d_in[0];
    const float* cosp   = (const float*)d_in[1];
    const float* sinp   = (const float*)d_in[2];
    const float* w_qkv  = (const float*)d_in[3];
    const float* b_qkv  = (const float*)d_in[4];
    const float* w_proj = (const float*)d_in[5];
    const float* b_proj = (const float*)d_in[6];
    float* out = (float*)d_out;

    char* ws = (char*)d_ws;
    u16* xb     = (u16*)(ws);
    u16* aout   = (u16*)(ws);              // overlaps xb (dead after gemm1)
    u16* wqkvT  = (u16*)(ws + 14180352);
    u16* wprojT = (u16*)(ws + 17719296);
    u16* qkv    = (u16*)(ws + 18898944);
    u16* VtG    = (u16*)(ws + 47259648);

    f32_to_bf16<<<6924, 256, 0, stream>>>(x, xb, 7090176);
    transpose_w<<<dim3(96, 24), 256, 0, stream>>>(w_qkv, w_proj, wqkvT, wprojT);
    gemm_bt<2><<<dim3(73, 18), 512, 0, stream>>>(xb, wqkvT, b_qkv, qkv,
                                                 cosp, sinp, VtG, 9232, 2304, 768);
    attn2<<<dim3(10, 192), 256, 0, stream>>>(qkv, VtG, aout);
    gemm_bt<1><<<dim3(73, 6), 512, 0, stream>>>(aout, wprojT, b_proj, out,
                                                nullptr, nullptr, nullptr, 9232, 768, 768);
}